// Round 1
// baseline (33018.097 us; speedup 1.0000x reference)
//
#include <hip/hip_runtime.h>
#include <hip/hip_cooperative_groups.h>

namespace cg = cooperative_groups;

typedef __attribute__((ext_vector_type(8))) short bf16x8;
typedef __attribute__((ext_vector_type(4))) float f32x4;

// ---- sizes ----
// B=128, T=256, EMB=512, H=1024, 4H=4096, VOC=32000
// out layout: [128][256][1024] f32, then hT [128][1024], then cT [128][1024]

__device__ __forceinline__ unsigned short f2bf(float f) {
  unsigned int u = __builtin_bit_cast(unsigned int, f);
  u = (u + 0x7FFFu + ((u >> 16) & 1u)) >> 16;  // RNE
  return (unsigned short)u;
}
__device__ __forceinline__ float bf2f(unsigned short s) {
  unsigned int u = ((unsigned int)s) << 16;
  return __builtin_bit_cast(float, u);
}
__device__ __forceinline__ void gload_lds16(const void* g, void* l) {
  __builtin_amdgcn_global_load_lds(
      (const __attribute__((address_space(1))) void*)g,
      (__attribute__((address_space(3))) void*)l, 16, 0, 0);
}
__device__ __forceinline__ float sigm(float x) { return 1.0f / (1.0f + __expf(-x)); }
__device__ __forceinline__ float tanh_f(float x) {
  float e = __expf(2.0f * x);
  return 1.0f - 2.0f / (e + 1.0f);  // saturates correctly, no NaN at +-inf
}

// ---------------- f32 -> bf16 elementwise (emb table) ----------------
__global__ void cvt_bf16_vec(const float4* __restrict__ in, ushort4* __restrict__ out, int n4) {
  int i = blockIdx.x * blockDim.x + threadIdx.x;
  int stride = gridDim.x * blockDim.x;
  for (; i < n4; i += stride) {
    float4 v = in[i];
    ushort4 o;
    o.x = f2bf(v.x); o.y = f2bf(v.y); o.z = f2bf(v.z); o.w = f2bf(v.w);
    out[i] = o;
  }
}

// ---- transpose f32 [K][N] -> bf16 [N][K]; SWZ: bake 16B-slot XOR swizzle ----
// W_sw[n][k0 + s*8 + e] = W[k0 + ((s ^ (n&7))*8 + e)][n]   (k0 = 64-blocks)
template <int SWZ>
__global__ void transpose_cvt(const float* __restrict__ in, unsigned short* __restrict__ out,
                              int K, int N) {
  __shared__ float tile[64][65];
  int k0 = blockIdx.x * 64, n0 = blockIdx.y * 64;
  int tid = threadIdx.x;
  int c = tid & 63, rq = tid >> 6;
#pragma unroll
  for (int rr = 0; rr < 16; ++rr) {
    int r = rr * 4 + rq;
    tile[r][c] = in[(size_t)(k0 + r) * N + n0 + c];
  }
  __syncthreads();
#pragma unroll
  for (int ww = 0; ww < 16; ++ww) {
    int nl = ww * 4 + rq;
    int n = n0 + nl;
    int kd = c;
    int ksrc;
    if (SWZ) {
      int s = kd >> 3, e = kd & 7;
      ksrc = ((((s ^ (n & 7)) & 7)) << 3) | e;
    } else {
      ksrc = kd;
    }
    out[(size_t)n * K + k0 + kd] = f2bf(tile[ksrc][nl]);
  }
}

// ---------------- pre = gather(emb,x) @ W + b   -> bf16 [32768][4096] ----------------
__global__ __launch_bounds__(256) void pregemm(
    const unsigned short* __restrict__ emb_bf, const int* __restrict__ x,
    const unsigned short* __restrict__ W_sw, const float* __restrict__ bias,
    unsigned short* __restrict__ pre) {
  __shared__ __align__(16) unsigned short A_lds[2][8192];  // 128 rows x 64 k (swizzled slots)
  __shared__ __align__(16) unsigned short B_lds[2][8192];
  int bid = blockIdx.x;
  int mtile = bid >> 5, ntile = bid & 31;  // 256 x 32
  int tid = threadIdx.x, wv = tid >> 6, ln = tid & 63;

  int xrow[4];
#pragma unroll
  for (int i = 0; i < 4; ++i) {
    int chunk = wv * 4 + i;
    int r = chunk * 8 + (ln >> 3);
    xrow[i] = x[mtile * 128 + r];
  }

  auto stage = [&](int buf, int kb) {
    int k0 = kb * 64;
#pragma unroll
    for (int i = 0; i < 4; ++i) {
      int chunk = wv * 4 + i;
      int r = chunk * 8 + (ln >> 3);
      // A: dest slot (ln&7) of row r must hold k-group (ln&7)^(r&7)
      const unsigned short* srcA =
          emb_bf + (size_t)xrow[i] * 512 + k0 + (((ln & 7) ^ (r & 7)) << 3);
      gload_lds16(srcA, &A_lds[buf][chunk * 512]);
      // B: swizzle pre-baked into W_sw, read linear
      const unsigned short* srcB =
          W_sw + (size_t)(ntile * 128 + r) * 512 + k0 + ((ln & 7) << 3);
      gload_lds16(srcB, &B_lds[buf][chunk * 512]);
    }
  };

  f32x4 acc[4][4];
#pragma unroll
  for (int i = 0; i < 4; ++i)
#pragma unroll
    for (int j = 0; j < 4; ++j) acc[i][j] = (f32x4)0.0f;

  int wm = wv >> 1, wn = wv & 1;
  stage(0, 0);
#pragma unroll 1
  for (int kb = 0; kb < 8; ++kb) {
    __syncthreads();                       // staged buf ready; prev compute done
    if (kb < 7) stage((kb + 1) & 1, kb + 1);
    int buf = kb & 1;
#pragma unroll
    for (int ks = 0; ks < 2; ++ks) {
      bf16x8 a[4], b[4];
#pragma unroll
      for (int f = 0; f < 4; ++f) {
        int r = wm * 64 + f * 16 + (ln & 15);
        int sa = ((ks * 4 + (ln >> 4)) ^ (r & 7)) & 7;
        a[f] = *(const bf16x8*)&A_lds[buf][r * 64 + sa * 8];
        int n = wn * 64 + f * 16 + (ln & 15);
        int sb = ((ks * 4 + (ln >> 4)) ^ (n & 7)) & 7;
        b[f] = *(const bf16x8*)&B_lds[buf][n * 64 + sb * 8];
      }
#pragma unroll
      for (int i = 0; i < 4; ++i)
#pragma unroll
        for (int j = 0; j < 4; ++j)
          acc[i][j] = __builtin_amdgcn_mfma_f32_16x16x32_bf16(a[i], b[j], acc[i][j], 0, 0, 0);
    }
  }
  // epilogue: + bias, store bf16
#pragma unroll
  for (int fm = 0; fm < 4; ++fm) {
#pragma unroll
    for (int fn = 0; fn < 4; ++fn) {
      int n = ntile * 128 + wn * 64 + fn * 16 + (ln & 15);
      float bn = bias[n];
      int m0 = mtile * 128 + wm * 64 + fm * 16 + ((ln >> 4) << 2);
#pragma unroll
      for (int i = 0; i < 4; ++i) {
        pre[(size_t)(m0 + i) * 4096 + n] = f2bf(acc[fm][fn][i] + bn);
      }
    }
  }
}

// ---------------- persistent LSTM recurrence ----------------
// grid 256 = 4 batch-groups (32 rows) x 64 j-slices (16 hidden cols); 512 thr = 8 waves.
// Each wave: K-range wv*128; U fragments resident in registers (64 VGPRs).
__global__ __launch_bounds__(512, 2) void lstm_kernel(
    const unsigned short* __restrict__ pre, const unsigned short* __restrict__ U_t,
    unsigned short* __restrict__ hbc, float* __restrict__ out) {
  cg::grid_group grid = cg::this_grid();
  __shared__ float zbuf[2][32][64];
  int bid = blockIdx.x;
  int bg = bid >> 6, js = bid & 63;
  int tid = threadIdx.x, wv = tid >> 6, ln = tid & 63;

  // resident B fragments: ub[gate][kk]; col = gate*1024 + js*16 + (ln&15)
  bf16x8 ub[4][4];
#pragma unroll
  for (int f = 0; f < 4; ++f) {
    int col = f * 1024 + js * 16 + (ln & 15);
#pragma unroll
    for (int kk = 0; kk < 4; ++kk) {
      int k = wv * 128 + kk * 32 + ((ln >> 4) << 3);
      ub[f][kk] = *(const bf16x8*)&U_t[(size_t)col * 1024 + k];
    }
  }

  // gate-phase ownership: 512 threads = 32 rows x 16 j
  int row = tid >> 4, j = tid & 15;
  int b = bg * 32 + row;
  int hcol = js * 16 + j;
  float c_state = 0.0f;
  size_t preb = ((size_t)b * 256) * 4096 + (size_t)(js * 16 + j);
  size_t outb = ((size_t)b * 256) * 1024 + (size_t)hcol;
  int arow0 = bg * 32 + (ln & 15);
  int arow1 = arow0 + 16;

#pragma unroll 1
  for (int t = 0; t < 256; ++t) {
    int p = t & 1;
    if (t > 0) {
      const unsigned short* hprev = hbc + (size_t)(p ^ 1) * 131072;
      f32x4 acc[2][4];
#pragma unroll
      for (int m = 0; m < 2; ++m)
#pragma unroll
        for (int f = 0; f < 4; ++f) acc[m][f] = (f32x4)0.0f;
#pragma unroll
      for (int kk = 0; kk < 4; ++kk) {
        int k = wv * 128 + kk * 32 + ((ln >> 4) << 3);
        bf16x8 a0 = *(const bf16x8*)&hprev[(size_t)arow0 * 1024 + k];
        bf16x8 a1 = *(const bf16x8*)&hprev[(size_t)arow1 * 1024 + k];
#pragma unroll
        for (int f = 0; f < 4; ++f) {
          acc[0][f] = __builtin_amdgcn_mfma_f32_16x16x32_bf16(a0, ub[f][kk], acc[0][f], 0, 0, 0);
          acc[1][f] = __builtin_amdgcn_mfma_f32_16x16x32_bf16(a1, ub[f][kk], acc[1][f], 0, 0, 0);
        }
      }
      // cross-wave K reduction: waves 0,1 store; waves 2..7 atomic-add
      int zs = wv & 1;
      if (wv < 2) {
#pragma unroll
        for (int m = 0; m < 2; ++m)
#pragma unroll
          for (int f = 0; f < 4; ++f)
#pragma unroll
            for (int i = 0; i < 4; ++i)
              zbuf[zs][m * 16 + ((ln >> 4) << 2) + i][f * 16 + (ln & 15)] = acc[m][f][i];
      }
      __syncthreads();
      if (wv >= 2) {
#pragma unroll
        for (int m = 0; m < 2; ++m)
#pragma unroll
          for (int f = 0; f < 4; ++f)
#pragma unroll
            for (int i = 0; i < 4; ++i)
              atomicAdd(&zbuf[zs][m * 16 + ((ln >> 4) << 2) + i][f * 16 + (ln & 15)],
                        acc[m][f][i]);
      }
      __syncthreads();
    }
    // gates (Keras order i,f,c,o)
    const unsigned short* pp = pre + preb + (size_t)t * 4096;
    float z0 = bf2f(pp[0]);
    float z1 = bf2f(pp[1024]);
    float z2 = bf2f(pp[2048]);
    float z3 = bf2f(pp[3072]);
    if (t > 0) {
      z0 += zbuf[0][row][j] + zbuf[1][row][j];
      z1 += zbuf[0][row][16 + j] + zbuf[1][row][16 + j];
      z2 += zbuf[0][row][32 + j] + zbuf[1][row][32 + j];
      z3 += zbuf[0][row][48 + j] + zbuf[1][row][48 + j];
    }
    float ig = sigm(z0), fg = sigm(z1), gg = tanh_f(z2), og = sigm(z3);
    c_state = fg * c_state + ig * gg;
    float h = og * tanh_f(c_state);
    out[outb + (size_t)t * 1024] = h;
    hbc[(size_t)p * 131072 + (size_t)b * 1024 + hcol] = f2bf(h);
    if (t == 255) {
      out[33554432 + (size_t)b * 1024 + hcol] = h;
      out[33554432 + 131072 + (size_t)b * 1024 + hcol] = c_state;
    }
    __threadfence();
    grid.sync();
    __threadfence();
  }
}

// ---------------- launcher ----------------
extern "C" void kernel_launch(void* const* d_in, const int* in_sizes, int n_in,
                              void* d_out, int out_size, void* d_ws, size_t ws_size,
                              hipStream_t stream) {
  const int*   x    = (const int*)d_in[0];
  // d_in[1] = hidden (ignored by reference module)
  const float* emb  = (const float*)d_in[2];
  const float* W    = (const float*)d_in[3];
  const float* U    = (const float*)d_in[4];
  const float* bias = (const float*)d_in[5];
  float* out = (float*)d_out;

  // workspace layout (bytes)
  const size_t OFS_PRE = 0;                     // 32768*4096*2 = 268435456
  const size_t OFS_EMB = 268435456;             // 32000*512*2  = 32768000
  const size_t OFS_WSW = 301203456;             // 4096*512*2   = 4194304
  const size_t OFS_UT  = 305397760;             // 4096*1024*2  = 8388608
  const size_t OFS_HBC = 313786368;             // 2*128*1024*2 = 524288
  const size_t WS_NEED = 314310656;
  if (ws_size < WS_NEED) return;  // insufficient scratch -> fail validation visibly

  char* ws = (char*)d_ws;
  unsigned short* pre_p = (unsigned short*)(ws + OFS_PRE);
  unsigned short* emb_p = (unsigned short*)(ws + OFS_EMB);
  unsigned short* wsw_p = (unsigned short*)(ws + OFS_WSW);
  unsigned short* ut_p  = (unsigned short*)(ws + OFS_UT);
  unsigned short* hbc_p = (unsigned short*)(ws + OFS_HBC);

  cvt_bf16_vec<<<2048, 256, 0, stream>>>((const float4*)emb, (ushort4*)emb_p, 4096000);
  transpose_cvt<1><<<dim3(8, 64), 256, 0, stream>>>(W, wsw_p, 512, 4096);
  transpose_cvt<0><<<dim3(16, 64), 256, 0, stream>>>(U, ut_p, 1024, 4096);
  pregemm<<<8192, 256, 0, stream>>>(emb_p, x, wsw_p, bias, pre_p);

  const unsigned short* pre_c = pre_p;
  const unsigned short* ut_c  = ut_p;
  unsigned short* hbc_v = hbc_p;
  float* out_v = out;
  void* args[] = {(void*)&pre_c, (void*)&ut_c, (void*)&hbc_v, (void*)&out_v};
  hipLaunchCooperativeKernel((const void*)lstm_kernel, dim3(256), dim3(512), args, 0, stream);
}

// Round 2
// 5875.018 us; speedup vs baseline: 5.6201x; 5.6201x over previous
//
#include <hip/hip_runtime.h>

typedef __attribute__((ext_vector_type(8))) short bf16x8;
typedef __attribute__((ext_vector_type(4))) float f32x4;

// ---- sizes ----
// B=128, T=256, EMB=512, H=1024, 4H=4096, VOC=32000
// out layout: [128][256][1024] f32, then hT [128][1024], then cT [128][1024]

__device__ __forceinline__ unsigned short f2bf(float f) {
  unsigned int u = __builtin_bit_cast(unsigned int, f);
  u = (u + 0x7FFFu + ((u >> 16) & 1u)) >> 16;  // RNE
  return (unsigned short)u;
}
__device__ __forceinline__ float bf2f(unsigned short s) {
  unsigned int u = ((unsigned int)s) << 16;
  return __builtin_bit_cast(float, u);
}
__device__ __forceinline__ void gload_lds16(const void* g, void* l) {
  __builtin_amdgcn_global_load_lds(
      (const __attribute__((address_space(1))) void*)g,
      (__attribute__((address_space(3))) void*)l, 16, 0, 0);
}
__device__ __forceinline__ float sigm(float x) { return 1.0f / (1.0f + __expf(-x)); }
__device__ __forceinline__ float tanh_f(float x) {
  float e = __expf(2.0f * x);
  return 1.0f - 2.0f / (e + 1.0f);  // saturates correctly, no NaN at +-inf
}

// device-coherent (agent-scope, sc0 sc1) 16B h load as two 8B atomic loads
__device__ __forceinline__ bf16x8 loadh16(const unsigned short* p) {
  unsigned long long* q = (unsigned long long*)p;
  unsigned long long lo = __hip_atomic_load(q, __ATOMIC_RELAXED, __HIP_MEMORY_SCOPE_AGENT);
  unsigned long long hi = __hip_atomic_load(q + 1, __ATOMIC_RELAXED, __HIP_MEMORY_SCOPE_AGENT);
  union { unsigned long long u[2]; bf16x8 v; } c;
  c.u[0] = lo; c.u[1] = hi;
  return c.v;
}

// ---------------- f32 -> bf16 elementwise (emb table) ----------------
__global__ void cvt_bf16_vec(const float4* __restrict__ in, ushort4* __restrict__ out, int n4) {
  int i = blockIdx.x * blockDim.x + threadIdx.x;
  int stride = gridDim.x * blockDim.x;
  for (; i < n4; i += stride) {
    float4 v = in[i];
    ushort4 o;
    o.x = f2bf(v.x); o.y = f2bf(v.y); o.z = f2bf(v.z); o.w = f2bf(v.w);
    out[i] = o;
  }
}

// ---- transpose f32 [K][N] -> bf16 [N][K]; SWZ: bake 16B-slot XOR swizzle ----
template <int SWZ>
__global__ void transpose_cvt(const float* __restrict__ in, unsigned short* __restrict__ out,
                              int K, int N) {
  __shared__ float tile[64][65];
  int k0 = blockIdx.x * 64, n0 = blockIdx.y * 64;
  int tid = threadIdx.x;
  int c = tid & 63, rq = tid >> 6;
#pragma unroll
  for (int rr = 0; rr < 16; ++rr) {
    int r = rr * 4 + rq;
    tile[r][c] = in[(size_t)(k0 + r) * N + n0 + c];
  }
  __syncthreads();
#pragma unroll
  for (int ww = 0; ww < 16; ++ww) {
    int nl = ww * 4 + rq;
    int n = n0 + nl;
    int kd = c;
    int ksrc;
    if (SWZ) {
      int s = kd >> 3, e = kd & 7;
      ksrc = ((((s ^ (n & 7)) & 7)) << 3) | e;
    } else {
      ksrc = kd;
    }
    out[(size_t)n * K + k0 + kd] = f2bf(tile[ksrc][nl]);
  }
}

// ---------------- pre = gather(emb,x) @ W + b   -> bf16 [32768][4096] ----------------
__global__ __launch_bounds__(256) void pregemm(
    const unsigned short* __restrict__ emb_bf, const int* __restrict__ x,
    const unsigned short* __restrict__ W_sw, const float* __restrict__ bias,
    unsigned short* __restrict__ pre) {
  __shared__ __align__(16) unsigned short A_lds[2][8192];  // 128 rows x 64 k (swizzled slots)
  __shared__ __align__(16) unsigned short B_lds[2][8192];
  int bid = blockIdx.x;
  int mtile = bid >> 5, ntile = bid & 31;  // 256 x 32
  int tid = threadIdx.x, wv = tid >> 6, ln = tid & 63;

  int xrow[4];
#pragma unroll
  for (int i = 0; i < 4; ++i) {
    int chunk = wv * 4 + i;
    int r = chunk * 8 + (ln >> 3);
    xrow[i] = x[mtile * 128 + r];
  }

  auto stage = [&](int buf, int kb) {
    int k0 = kb * 64;
#pragma unroll
    for (int i = 0; i < 4; ++i) {
      int chunk = wv * 4 + i;
      int r = chunk * 8 + (ln >> 3);
      const unsigned short* srcA =
          emb_bf + (size_t)xrow[i] * 512 + k0 + (((ln & 7) ^ (r & 7)) << 3);
      gload_lds16(srcA, &A_lds[buf][chunk * 512]);
      const unsigned short* srcB =
          W_sw + (size_t)(ntile * 128 + r) * 512 + k0 + ((ln & 7) << 3);
      gload_lds16(srcB, &B_lds[buf][chunk * 512]);
    }
  };

  f32x4 acc[4][4];
#pragma unroll
  for (int i = 0; i < 4; ++i)
#pragma unroll
    for (int j = 0; j < 4; ++j) acc[i][j] = (f32x4)0.0f;

  int wm = wv >> 1, wn = wv & 1;
  stage(0, 0);
#pragma unroll 1
  for (int kb = 0; kb < 8; ++kb) {
    __syncthreads();
    if (kb < 7) stage((kb + 1) & 1, kb + 1);
    int buf = kb & 1;
#pragma unroll
    for (int ks = 0; ks < 2; ++ks) {
      bf16x8 a[4], b[4];
#pragma unroll
      for (int f = 0; f < 4; ++f) {
        int r = wm * 64 + f * 16 + (ln & 15);
        int sa = ((ks * 4 + (ln >> 4)) ^ (r & 7)) & 7;
        a[f] = *(const bf16x8*)&A_lds[buf][r * 64 + sa * 8];
        int n = wn * 64 + f * 16 + (ln & 15);
        int sb = ((ks * 4 + (ln >> 4)) ^ (n & 7)) & 7;
        b[f] = *(const bf16x8*)&B_lds[buf][n * 64 + sb * 8];
      }
#pragma unroll
      for (int i = 0; i < 4; ++i)
#pragma unroll
        for (int j = 0; j < 4; ++j)
          acc[i][j] = __builtin_amdgcn_mfma_f32_16x16x32_bf16(a[i], b[j], acc[i][j], 0, 0, 0);
    }
  }
#pragma unroll
  for (int fm = 0; fm < 4; ++fm) {
#pragma unroll
    for (int fn = 0; fn < 4; ++fn) {
      int n = ntile * 128 + wn * 64 + fn * 16 + (ln & 15);
      float bn = bias[n];
      int m0 = mtile * 128 + wm * 64 + fm * 16 + ((ln >> 4) << 2);
#pragma unroll
      for (int i = 0; i < 4; ++i) {
        pre[(size_t)(m0 + i) * 4096 + n] = f2bf(acc[fm][fn][i] + bn);
      }
    }
  }
}

// ---------------- counter init ----------------
__global__ void init_cnt(unsigned int* cnt) {
  if (threadIdx.x < 4)
    __hip_atomic_store(&cnt[threadIdx.x * 32], 0u, __ATOMIC_RELAXED, __HIP_MEMORY_SCOPE_AGENT);
}

// ---------------- persistent LSTM recurrence ----------------
// grid 256 = 4 batch-groups (32 rows) x 64 j-slices (16 hidden cols); 512 thr = 8 waves.
// Per-bg monotonic counter barrier; h exchanged via agent-scope (sc1) stores/loads ->
// no L2 flushes, no grid.sync.
__global__ __launch_bounds__(512, 2) void lstm_kernel(
    const unsigned short* __restrict__ pre, const unsigned short* __restrict__ U_t,
    unsigned short* __restrict__ hbc, float* __restrict__ out, unsigned int* cnt) {
  __shared__ float zbuf[2][32][64];
  int bid = blockIdx.x;
  int bg = bid >> 6, js = bid & 63;
  int tid = threadIdx.x, wv = tid >> 6, ln = tid & 63;
  unsigned int* cntp = cnt + bg * 32;

  // resident B fragments: ub[gate][kk]; col = gate*1024 + js*16 + (ln&15)
  bf16x8 ub[4][4];
#pragma unroll
  for (int f = 0; f < 4; ++f) {
    int col = f * 1024 + js * 16 + (ln & 15);
#pragma unroll
    for (int kk = 0; kk < 4; ++kk) {
      int k = wv * 128 + kk * 32 + ((ln >> 4) << 3);
      ub[f][kk] = *(const bf16x8*)&U_t[(size_t)col * 1024 + k];
    }
  }

  // gate-phase ownership: 512 threads = 32 rows x 16 j
  int row = tid >> 4, j = tid & 15;
  int b = bg * 32 + row;
  int hcol = js * 16 + j;
  float c_state = 0.0f;
  size_t preb = ((size_t)b * 256) * 4096 + (size_t)(js * 16 + j);
  size_t outb = ((size_t)b * 256) * 1024 + (size_t)hcol;
  int arow0 = bg * 32 + (ln & 15);
  int arow1 = arow0 + 16;

  // prefetch pre[t=0]
  float z0n, z1n, z2n, z3n;
  {
    const unsigned short* pp = pre + preb;
    z0n = bf2f(pp[0]); z1n = bf2f(pp[1024]); z2n = bf2f(pp[2048]); z3n = bf2f(pp[3072]);
  }

#pragma unroll 1
  for (int t = 0; t < 256; ++t) {
    int p = t & 1;
    if (t > 0) {
      // wait until all 64 WGs of this bg published h_{t-1}
      if (tid == 0) {
        unsigned int tgt = 64u * (unsigned int)t;
        while (__hip_atomic_load(cntp, __ATOMIC_RELAXED, __HIP_MEMORY_SCOPE_AGENT) < tgt)
          __builtin_amdgcn_s_sleep(1);
      }
      __syncthreads();
      const unsigned short* hprev = hbc + (size_t)(p ^ 1) * 131072;
      f32x4 acc[2][4];
#pragma unroll
      for (int m = 0; m < 2; ++m)
#pragma unroll
        for (int f = 0; f < 4; ++f) acc[m][f] = (f32x4)0.0f;
#pragma unroll
      for (int kk = 0; kk < 4; ++kk) {
        int k = wv * 128 + kk * 32 + ((ln >> 4) << 3);
        bf16x8 a0 = loadh16(&hprev[(size_t)arow0 * 1024 + k]);
        bf16x8 a1 = loadh16(&hprev[(size_t)arow1 * 1024 + k]);
#pragma unroll
        for (int f = 0; f < 4; ++f) {
          acc[0][f] = __builtin_amdgcn_mfma_f32_16x16x32_bf16(a0, ub[f][kk], acc[0][f], 0, 0, 0);
          acc[1][f] = __builtin_amdgcn_mfma_f32_16x16x32_bf16(a1, ub[f][kk], acc[1][f], 0, 0, 0);
        }
      }
      // cross-wave K reduction: waves 0,1 store; waves 2..7 atomic-add
      int zs = wv & 1;
      if (wv < 2) {
#pragma unroll
        for (int m = 0; m < 2; ++m)
#pragma unroll
          for (int f = 0; f < 4; ++f)
#pragma unroll
            for (int i = 0; i < 4; ++i)
              zbuf[zs][m * 16 + ((ln >> 4) << 2) + i][f * 16 + (ln & 15)] = acc[m][f][i];
      }
      __syncthreads();
      if (wv >= 2) {
#pragma unroll
        for (int m = 0; m < 2; ++m)
#pragma unroll
          for (int f = 0; f < 4; ++f)
#pragma unroll
            for (int i = 0; i < 4; ++i)
              atomicAdd(&zbuf[zs][m * 16 + ((ln >> 4) << 2) + i][f * 16 + (ln & 15)],
                        acc[m][f][i]);
      }
      __syncthreads();
    }
    // gates (Keras order i,f,c,o) from prefetched pre values
    float z0 = z0n, z1 = z1n, z2 = z2n, z3 = z3n;
    if (t < 255) {  // prefetch next step early; hides under barrier/store latency
      const unsigned short* pp = pre + preb + (size_t)(t + 1) * 4096;
      z0n = bf2f(pp[0]); z1n = bf2f(pp[1024]); z2n = bf2f(pp[2048]); z3n = bf2f(pp[3072]);
    }
    if (t > 0) {
      z0 += zbuf[0][row][j] + zbuf[1][row][j];
      z1 += zbuf[0][row][16 + j] + zbuf[1][row][16 + j];
      z2 += zbuf[0][row][32 + j] + zbuf[1][row][32 + j];
      z3 += zbuf[0][row][48 + j] + zbuf[1][row][48 + j];
    }
    float ig = sigm(z0), fg = sigm(z1), gg = tanh_f(z2), og = sigm(z3);
    c_state = fg * c_state + ig * gg;
    float h = og * tanh_f(c_state);
    out[outb + (size_t)t * 1024] = h;
    // device-coherent h publish (write-through to memory-side coherence point)
    __hip_atomic_store(&hbc[(size_t)p * 131072 + (size_t)b * 1024 + hcol], f2bf(h),
                       __ATOMIC_RELAXED, __HIP_MEMORY_SCOPE_AGENT);
    if (t == 255) {
      out[33554432 + (size_t)b * 1024 + hcol] = h;
      out[33554432 + 131072 + (size_t)b * 1024 + hcol] = c_state;
    } else {
      // __syncthreads lowers with s_waitcnt vmcnt(0) first -> all waves' sc1 h-stores
      // are at the coherence point before the signal below.
      __syncthreads();
      if (tid == 0)
        __hip_atomic_fetch_add(cntp, 1u, __ATOMIC_RELAXED, __HIP_MEMORY_SCOPE_AGENT);
    }
  }
}

// ---------------- launcher ----------------
extern "C" void kernel_launch(void* const* d_in, const int* in_sizes, int n_in,
                              void* d_out, int out_size, void* d_ws, size_t ws_size,
                              hipStream_t stream) {
  const int*   x    = (const int*)d_in[0];
  // d_in[1] = hidden (ignored by reference module)
  const float* emb  = (const float*)d_in[2];
  const float* W    = (const float*)d_in[3];
  const float* U    = (const float*)d_in[4];
  const float* bias = (const float*)d_in[5];
  float* out = (float*)d_out;

  // workspace layout (bytes)
  const size_t OFS_PRE = 0;                     // 32768*4096*2 = 268435456
  const size_t OFS_EMB = 268435456;             // 32000*512*2  = 32768000
  const size_t OFS_WSW = 301203456;             // 4096*512*2   = 4194304
  const size_t OFS_UT  = 305397760;             // 4096*1024*2  = 8388608
  const size_t OFS_HBC = 313786368;             // 2*128*1024*2 = 524288
  const size_t OFS_CNT = 314310656;             // 4 * 128B     = 512
  const size_t WS_NEED = 314311168;
  if (ws_size < WS_NEED) return;  // insufficient scratch -> fail validation visibly

  char* ws = (char*)d_ws;
  unsigned short* pre_p = (unsigned short*)(ws + OFS_PRE);
  unsigned short* emb_p = (unsigned short*)(ws + OFS_EMB);
  unsigned short* wsw_p = (unsigned short*)(ws + OFS_WSW);
  unsigned short* ut_p  = (unsigned short*)(ws + OFS_UT);
  unsigned short* hbc_p = (unsigned short*)(ws + OFS_HBC);
  unsigned int*   cnt_p = (unsigned int*)(ws + OFS_CNT);

  cvt_bf16_vec<<<2048, 256, 0, stream>>>((const float4*)emb, (ushort4*)emb_p, 4096000);
  transpose_cvt<1><<<dim3(8, 64), 256, 0, stream>>>(W, wsw_p, 512, 4096);
  transpose_cvt<0><<<dim3(16, 64), 256, 0, stream>>>(U, ut_p, 1024, 4096);
  init_cnt<<<1, 64, 0, stream>>>(cnt_p);
  pregemm<<<8192, 256, 0, stream>>>(emb_p, x, wsw_p, bias, pre_p);

  const unsigned short* pre_c = pre_p;
  const unsigned short* ut_c  = ut_p;
  unsigned short* hbc_v = hbc_p;
  float* out_v = out;
  unsigned int* cnt_v = cnt_p;
  void* args[] = {(void*)&pre_c, (void*)&ut_c, (void*)&hbc_v, (void*)&out_v, (void*)&cnt_v};
  hipLaunchCooperativeKernel((const void*)lstm_kernel, dim3(256), dim3(512), args, 0, stream);
}

// Round 4
// 2704.549 us; speedup vs baseline: 12.2084x; 2.1723x over previous
//
#include <hip/hip_runtime.h>

typedef __attribute__((ext_vector_type(8))) short bf16x8;
typedef __attribute__((ext_vector_type(4))) float f32x4;

// ---- sizes ----
// B=128, T=256, EMB=512, H=1024, 4H=4096, VOC=32000
// out layout: [128][256][1024] f32, then hT [128][1024], then cT [128][1024]

__device__ __forceinline__ unsigned short f2bf(float f) {
  unsigned int u = __builtin_bit_cast(unsigned int, f);
  u = (u + 0x7FFFu + ((u >> 16) & 1u)) >> 16;  // RNE
  return (unsigned short)u;
}
__device__ __forceinline__ float bf2f(unsigned short s) {
  unsigned int u = ((unsigned int)s) << 16;
  return __builtin_bit_cast(float, u);
}
__device__ __forceinline__ void gload_lds16(const void* g, void* l) {
  __builtin_amdgcn_global_load_lds(
      (const __attribute__((address_space(1))) void*)g,
      (__attribute__((address_space(3))) void*)l, 16, 0, 0);
}
__device__ __forceinline__ float sigm(float x) { return 1.0f / (1.0f + __expf(-x)); }
__device__ __forceinline__ float tanh_f(float x) {
  float e = __expf(2.0f * x);
  return 1.0f - 2.0f / (e + 1.0f);  // saturates correctly, no NaN at +-inf
}

// device-coherent (agent-scope) 16B h load as two 8B atomic loads
__device__ __forceinline__ bf16x8 loadh16(const unsigned short* p) {
  unsigned long long* q = (unsigned long long*)p;
  unsigned long long lo = __hip_atomic_load(q, __ATOMIC_RELAXED, __HIP_MEMORY_SCOPE_AGENT);
  unsigned long long hi = __hip_atomic_load(q + 1, __ATOMIC_RELAXED, __HIP_MEMORY_SCOPE_AGENT);
  union { unsigned long long u[2]; bf16x8 v; } c;
  c.u[0] = lo; c.u[1] = hi;
  return c.v;
}

// ---------------- f32 -> bf16 elementwise (emb table) ----------------
__global__ void cvt_bf16_vec(const float4* __restrict__ in, ushort4* __restrict__ out, int n4) {
  int i = blockIdx.x * blockDim.x + threadIdx.x;
  int stride = gridDim.x * blockDim.x;
  for (; i < n4; i += stride) {
    float4 v = in[i];
    ushort4 o;
    o.x = f2bf(v.x); o.y = f2bf(v.y); o.z = f2bf(v.z); o.w = f2bf(v.w);
    out[i] = o;
  }
}

// ---- transpose f32 [K][N] -> bf16 [N][K]; SWZ: bake 16B-slot XOR swizzle ----
template <int SWZ>
__global__ void transpose_cvt(const float* __restrict__ in, unsigned short* __restrict__ out,
                              int K, int N) {
  __shared__ float tile[64][65];
  int k0 = blockIdx.x * 64, n0 = blockIdx.y * 64;
  int tid = threadIdx.x;
  int c = tid & 63, rq = tid >> 6;
#pragma unroll
  for (int rr = 0; rr < 16; ++rr) {
    int r = rr * 4 + rq;
    tile[r][c] = in[(size_t)(k0 + r) * N + n0 + c];
  }
  __syncthreads();
#pragma unroll
  for (int ww = 0; ww < 16; ++ww) {
    int nl = ww * 4 + rq;
    int n = n0 + nl;
    int kd = c;
    int ksrc;
    if (SWZ) {
      int s = kd >> 3, e = kd & 7;
      ksrc = ((((s ^ (n & 7)) & 7)) << 3) | e;
    } else {
      ksrc = kd;
    }
    out[(size_t)n * K + k0 + kd] = f2bf(tile[ksrc][nl]);
  }
}

// ---------------- pre = gather(emb,x) @ W + b   -> bf16 [32768][4096] ----------------
__global__ __launch_bounds__(256) void pregemm(
    const unsigned short* __restrict__ emb_bf, const int* __restrict__ x,
    const unsigned short* __restrict__ W_sw, const float* __restrict__ bias,
    unsigned short* __restrict__ pre) {
  __shared__ __align__(16) unsigned short A_lds[2][8192];  // 128 rows x 64 k (swizzled slots)
  __shared__ __align__(16) unsigned short B_lds[2][8192];
  int bid = blockIdx.x;
  int mtile = bid >> 5, ntile = bid & 31;  // 256 x 32
  int tid = threadIdx.x, wv = tid >> 6, ln = tid & 63;

  int xrow[4];
#pragma unroll
  for (int i = 0; i < 4; ++i) {
    int chunk = wv * 4 + i;
    int r = chunk * 8 + (ln >> 3);
    xrow[i] = x[mtile * 128 + r];
  }

  auto stage = [&](int buf, int kb) {
    int k0 = kb * 64;
#pragma unroll
    for (int i = 0; i < 4; ++i) {
      int chunk = wv * 4 + i;
      int r = chunk * 8 + (ln >> 3);
      const unsigned short* srcA =
          emb_bf + (size_t)xrow[i] * 512 + k0 + (((ln & 7) ^ (r & 7)) << 3);
      gload_lds16(srcA, &A_lds[buf][chunk * 512]);
      const unsigned short* srcB =
          W_sw + (size_t)(ntile * 128 + r) * 512 + k0 + ((ln & 7) << 3);
      gload_lds16(srcB, &B_lds[buf][chunk * 512]);
    }
  };

  f32x4 acc[4][4];
#pragma unroll
  for (int i = 0; i < 4; ++i)
#pragma unroll
    for (int j = 0; j < 4; ++j) acc[i][j] = (f32x4)0.0f;

  int wm = wv >> 1, wn = wv & 1;
  stage(0, 0);
#pragma unroll 1
  for (int kb = 0; kb < 8; ++kb) {
    __syncthreads();
    if (kb < 7) stage((kb + 1) & 1, kb + 1);
    int buf = kb & 1;
#pragma unroll
    for (int ks = 0; ks < 2; ++ks) {
      bf16x8 a[4], b[4];
#pragma unroll
      for (int f = 0; f < 4; ++f) {
        int r = wm * 64 + f * 16 + (ln & 15);
        int sa = ((ks * 4 + (ln >> 4)) ^ (r & 7)) & 7;
        a[f] = *(const bf16x8*)&A_lds[buf][r * 64 + sa * 8];
        int n = wn * 64 + f * 16 + (ln & 15);
        int sb = ((ks * 4 + (ln >> 4)) ^ (n & 7)) & 7;
        b[f] = *(const bf16x8*)&B_lds[buf][n * 64 + sb * 8];
      }
#pragma unroll
      for (int i = 0; i < 4; ++i)
#pragma unroll
        for (int j = 0; j < 4; ++j)
          acc[i][j] = __builtin_amdgcn_mfma_f32_16x16x32_bf16(a[i], b[j], acc[i][j], 0, 0, 0);
    }
  }
#pragma unroll
  for (int fm = 0; fm < 4; ++fm) {
#pragma unroll
    for (int fn = 0; fn < 4; ++fn) {
      int n = ntile * 128 + wn * 64 + fn * 16 + (ln & 15);
      float bn = bias[n];
      int m0 = mtile * 128 + wm * 64 + fm * 16 + ((ln >> 4) << 2);
#pragma unroll
      for (int i = 0; i < 4; ++i) {
        pre[(size_t)(m0 + i) * 4096 + n] = f2bf(acc[fm][fn][i] + bn);
      }
    }
  }
}

// ---------------- flag init ----------------
__global__ void init_flags(unsigned int* f) {
  __hip_atomic_store(&f[threadIdx.x], 0u, __ATOMIC_RELAXED, __HIP_MEMORY_SCOPE_AGENT);
}

// ---------------- persistent LSTM recurrence ----------------
// grid 256 = 4 batch-groups (32 rows) x 64 j-slices (16 hidden cols); 512 thr = 8 waves.
// Publish: per-WG flag word (64 PARALLEL stores per bg, no serialized RMW), preceded by
// an EXPLICIT s_waitcnt vmcnt(0) in every thread + barrier, so the flag store is
// provably ordered after all waves' sc1 h-stores complete at the coherence point
// (do NOT rely on __syncthreads emitting the vmcnt drain).
// Consume: wave 0 polls all 64 flags (one per lane) then barrier -> round-2-equivalent
// all-producer gating semantics.
__global__ __launch_bounds__(512, 2) void lstm_kernel(
    const unsigned short* __restrict__ pre, const unsigned short* __restrict__ U_t,
    unsigned short* __restrict__ hbc, float* __restrict__ out, unsigned int* flags) {
  __shared__ float zbuf[8][32][68];  // [wave slice][row][z-col], padded
  int bid = blockIdx.x;
  int bg = bid >> 6, js = bid & 63;
  int tid = threadIdx.x, wv = tid >> 6, ln = tid & 63;

  // resident B fragments: ub[gate][kk]; col = gate*1024 + js*16 + (ln&15)
  bf16x8 ub[4][4];
#pragma unroll
  for (int f = 0; f < 4; ++f) {
    int col = f * 1024 + js * 16 + (ln & 15);
#pragma unroll
    for (int kk = 0; kk < 4; ++kk) {
      int k = wv * 128 + kk * 32 + ((ln >> 4) << 3);
      ub[f][kk] = *(const bf16x8*)&U_t[(size_t)col * 1024 + k];
    }
  }

  // gate-phase ownership: 512 threads = 32 rows x 16 j
  int row = tid >> 4, j = tid & 15;
  int b = bg * 32 + row;
  int hcol = js * 16 + j;
  float c_state = 0.0f;
  size_t preb = ((size_t)b * 256) * 4096 + (size_t)(js * 16 + j);
  size_t outb = ((size_t)b * 256) * 1024 + (size_t)hcol;
  int arow0 = bg * 32 + (ln & 15);
  int arow1 = arow0 + 16;
  const unsigned int* pollp = flags + bg * 64 + ln;  // wave 0: one flag per lane
  unsigned int* myflag = flags + bg * 64 + js;

  // prefetch pre[t=0]
  float z0n, z1n, z2n, z3n;
  {
    const unsigned short* pp = pre + preb;
    z0n = bf2f(pp[0]); z1n = bf2f(pp[1024]); z2n = bf2f(pp[2048]); z3n = bf2f(pp[3072]);
  }

#pragma unroll 1
  for (int t = 0; t < 256; ++t) {
    int p = t & 1;
    if (t > 0) {
      // gate on ALL 64 producers of this bg having published h_{t-1}
      if (wv == 0) {
        while (!__all((int)(__hip_atomic_load(pollp, __ATOMIC_RELAXED,
                                              __HIP_MEMORY_SCOPE_AGENT) >= (unsigned)t)))
          __builtin_amdgcn_s_sleep(1);
      }
      __syncthreads();  // SYNC0: release all waves to read h_{t-1}
      const unsigned short* hprev = hbc + (size_t)(p ^ 1) * 131072;
      f32x4 acc[2][4];
#pragma unroll
      for (int m = 0; m < 2; ++m)
#pragma unroll
        for (int f = 0; f < 4; ++f) acc[m][f] = (f32x4)0.0f;
#pragma unroll
      for (int kk = 0; kk < 4; ++kk) {
        int k = wv * 128 + kk * 32 + ((ln >> 4) << 3);
        bf16x8 a0 = loadh16(&hprev[(size_t)arow0 * 1024 + k]);
        bf16x8 a1 = loadh16(&hprev[(size_t)arow1 * 1024 + k]);
#pragma unroll
        for (int f = 0; f < 4; ++f) {
          acc[0][f] = __builtin_amdgcn_mfma_f32_16x16x32_bf16(a0, ub[f][kk], acc[0][f], 0, 0, 0);
          acc[1][f] = __builtin_amdgcn_mfma_f32_16x16x32_bf16(a1, ub[f][kk], acc[1][f], 0, 0, 0);
        }
      }
      // conflict-light private-slice writes (2-way max)
#pragma unroll
      for (int m = 0; m < 2; ++m)
#pragma unroll
        for (int f = 0; f < 4; ++f)
#pragma unroll
          for (int i = 0; i < 4; ++i)
            zbuf[wv][m * 16 + ((ln >> 4) << 2) + i][f * 16 + (ln & 15)] = acc[m][f][i];
      __syncthreads();  // SYNC1: all z slices visible to gate phase
    }
    // gates (Keras order i,f,c,o) from prefetched pre values
    float z0 = z0n, z1 = z1n, z2 = z2n, z3 = z3n;
    if (t < 255) {  // prefetch next step early; hides under store/flag latency
      const unsigned short* pp = pre + preb + (size_t)(t + 1) * 4096;
      z0n = bf2f(pp[0]); z1n = bf2f(pp[1024]); z2n = bf2f(pp[2048]); z3n = bf2f(pp[3072]);
    }
    if (t > 0) {
      float s0 = 0.f, s1 = 0.f, s2 = 0.f, s3 = 0.f;
#pragma unroll
      for (int s = 0; s < 8; ++s) {
        s0 += zbuf[s][row][j];
        s1 += zbuf[s][row][16 + j];
        s2 += zbuf[s][row][32 + j];
        s3 += zbuf[s][row][48 + j];
      }
      z0 += s0; z1 += s1; z2 += s2; z3 += s3;
    }
    float ig = sigm(z0), fg = sigm(z1), gg = tanh_f(z2), og = sigm(z3);
    c_state = fg * c_state + ig * gg;
    float h = og * tanh_f(c_state);
    // device-coherent h publish first (critical path), then bulk out store
    __hip_atomic_store(&hbc[(size_t)p * 131072 + (size_t)b * 1024 + hcol], f2bf(h),
                       __ATOMIC_RELAXED, __HIP_MEMORY_SCOPE_AGENT);
    out[outb + (size_t)t * 1024] = h;
    if (t == 255) {
      out[33554432 + (size_t)b * 1024 + hcol] = h;
      out[33554432 + 131072 + (size_t)b * 1024 + hcol] = c_state;
    } else {
      // EXPLICIT release drain: every wave waits for its own h-store to reach the
      // coherence point BEFORE the barrier; flag store after the barrier is then
      // ordered after ALL waves' h-stores. Also orders zbuf reads(t) vs writes(t+1).
      asm volatile("s_waitcnt vmcnt(0)" ::: "memory");
      __syncthreads();  // SYNC2
      if (tid == 0)
        __hip_atomic_store(myflag, (unsigned)(t + 1), __ATOMIC_RELAXED,
                           __HIP_MEMORY_SCOPE_AGENT);
    }
  }
}

// ---------------- launcher ----------------
extern "C" void kernel_launch(void* const* d_in, const int* in_sizes, int n_in,
                              void* d_out, int out_size, void* d_ws, size_t ws_size,
                              hipStream_t stream) {
  const int*   x    = (const int*)d_in[0];
  // d_in[1] = hidden (ignored by reference module)
  const float* emb  = (const float*)d_in[2];
  const float* W    = (const float*)d_in[3];
  const float* U    = (const float*)d_in[4];
  const float* bias = (const float*)d_in[5];
  float* out = (float*)d_out;

  // workspace layout (bytes)
  const size_t OFS_PRE = 0;                     // 32768*4096*2 = 268435456
  const size_t OFS_EMB = 268435456;             // 32000*512*2  = 32768000
  const size_t OFS_WSW = 301203456;             // 4096*512*2   = 4194304
  const size_t OFS_UT  = 305397760;             // 4096*1024*2  = 8388608
  const size_t OFS_HBC = 313786368;             // 2*128*1024*2 = 524288
  const size_t OFS_FLG = 314310656;             // 256 * 4B     = 1024
  const size_t WS_NEED = 314311680;
  if (ws_size < WS_NEED) return;  // insufficient scratch -> fail validation visibly

  char* ws = (char*)d_ws;
  unsigned short* pre_p = (unsigned short*)(ws + OFS_PRE);
  unsigned short* emb_p = (unsigned short*)(ws + OFS_EMB);
  unsigned short* wsw_p = (unsigned short*)(ws + OFS_WSW);
  unsigned short* ut_p  = (unsigned short*)(ws + OFS_UT);
  unsigned short* hbc_p = (unsigned short*)(ws + OFS_HBC);
  unsigned int*   flg_p = (unsigned int*)(ws + OFS_FLG);

  cvt_bf16_vec<<<2048, 256, 0, stream>>>((const float4*)emb, (ushort4*)emb_p, 4096000);
  transpose_cvt<1><<<dim3(8, 64), 256, 0, stream>>>(W, wsw_p, 512, 4096);
  transpose_cvt<0><<<dim3(16, 64), 256, 0, stream>>>(U, ut_p, 1024, 4096);
  init_flags<<<1, 256, 0, stream>>>(flg_p);
  pregemm<<<8192, 256, 0, stream>>>(emb_p, x, wsw_p, bias, pre_p);

  const unsigned short* pre_c = pre_p;
  const unsigned short* ut_c  = ut_p;
  unsigned short* hbc_v = hbc_p;
  float* out_v = out;
  unsigned int* flg_v = flg_p;
  void* args[] = {(void*)&pre_c, (void*)&ut_c, (void*)&hbc_v, (void*)&out_v, (void*)&flg_v};
  hipLaunchCooperativeKernel((const void*)lstm_kernel, dim3(256), dim3(512), args, 0, stream);
}

// Round 7
// 1878.260 us; speedup vs baseline: 17.5791x; 1.4399x over previous
//
#include <hip/hip_runtime.h>

typedef __attribute__((ext_vector_type(8))) short bf16x8;
typedef __attribute__((ext_vector_type(4))) float f32x4;

// ---- sizes ----
// B=128, T=256, EMB=512, H=1024, 4H=4096, VOC=32000
// out layout: [128][256][1024] f32, then hT [128][1024], then cT [128][1024]

__device__ __forceinline__ unsigned short f2bf(float f) {
  unsigned int u = __builtin_bit_cast(unsigned int, f);
  u = (u + 0x7FFFu + ((u >> 16) & 1u)) >> 16;  // RNE
  return (unsigned short)u;
}
__device__ __forceinline__ float bf2f(unsigned short s) {
  unsigned int u = ((unsigned int)s) << 16;
  return __builtin_bit_cast(float, u);
}
__device__ __forceinline__ void gload_lds16(const void* g, void* l) {
  __builtin_amdgcn_global_load_lds(
      (const __attribute__((address_space(1))) void*)g,
      (__attribute__((address_space(3))) void*)l, 16, 0, 0);
}
__device__ __forceinline__ float sigm(float x) { return 1.0f / (1.0f + __expf(-x)); }
__device__ __forceinline__ float tanh_f(float x) {
  float e = __expf(2.0f * x);
  return 1.0f - 2.0f / (e + 1.0f);  // saturates correctly, no NaN at +-inf
}

// device-coherent (agent-scope) 16B h load as two 8B atomic loads
__device__ __forceinline__ bf16x8 loadh16(const unsigned short* p) {
  unsigned long long* q = (unsigned long long*)p;
  unsigned long long lo = __hip_atomic_load(q, __ATOMIC_RELAXED, __HIP_MEMORY_SCOPE_AGENT);
  unsigned long long hi = __hip_atomic_load(q + 1, __ATOMIC_RELAXED, __HIP_MEMORY_SCOPE_AGENT);
  union { unsigned long long u[2]; bf16x8 v; } c;
  c.u[0] = lo; c.u[1] = hi;
  return c.v;
}

// ---------------- f32 -> bf16 elementwise (emb table) ----------------
__global__ void cvt_bf16_vec(const float4* __restrict__ in, ushort4* __restrict__ out, int n4) {
  int i = blockIdx.x * blockDim.x + threadIdx.x;
  int stride = gridDim.x * blockDim.x;
  for (; i < n4; i += stride) {
    float4 v = in[i];
    ushort4 o;
    o.x = f2bf(v.x); o.y = f2bf(v.y); o.z = f2bf(v.z); o.w = f2bf(v.w);
    out[i] = o;
  }
}

// ---- transpose f32 [K][N] -> bf16 [N][K]; SWZ: bake 16B-slot XOR swizzle ----
template <int SWZ>
__global__ void transpose_cvt(const float* __restrict__ in, unsigned short* __restrict__ out,
                              int K, int N) {
  __shared__ float tile[64][65];
  int k0 = blockIdx.x * 64, n0 = blockIdx.y * 64;
  int tid = threadIdx.x;
  int c = tid & 63, rq = tid >> 6;
#pragma unroll
  for (int rr = 0; rr < 16; ++rr) {
    int r = rr * 4 + rq;
    tile[r][c] = in[(size_t)(k0 + r) * N + n0 + c];
  }
  __syncthreads();
#pragma unroll
  for (int ww = 0; ww < 16; ++ww) {
    int nl = ww * 4 + rq;
    int n = n0 + nl;
    int kd = c;
    int ksrc;
    if (SWZ) {
      int s = kd >> 3, e = kd & 7;
      ksrc = ((((s ^ (n & 7)) & 7)) << 3) | e;
    } else {
      ksrc = kd;
    }
    out[(size_t)n * K + k0 + kd] = f2bf(tile[ksrc][nl]);
  }
}

// ---------------- pre = gather(emb,x) @ W + b   -> bf16 [32768][4096] ----------------
__global__ __launch_bounds__(256) void pregemm(
    const unsigned short* __restrict__ emb_bf, const int* __restrict__ x,
    const unsigned short* __restrict__ W_sw, const float* __restrict__ bias,
    unsigned short* __restrict__ pre) {
  __shared__ __align__(16) unsigned short A_lds[2][8192];  // 128 rows x 64 k (swizzled slots)
  __shared__ __align__(16) unsigned short B_lds[2][8192];
  int bid = blockIdx.x;
  int mtile = bid >> 5, ntile = bid & 31;  // 256 x 32
  int tid = threadIdx.x, wv = tid >> 6, ln = tid & 63;

  int xrow[4];
#pragma unroll
  for (int i = 0; i < 4; ++i) {
    int chunk = wv * 4 + i;
    int r = chunk * 8 + (ln >> 3);
    xrow[i] = x[mtile * 128 + r];
  }

  auto stage = [&](int buf, int kb) {
    int k0 = kb * 64;
#pragma unroll
    for (int i = 0; i < 4; ++i) {
      int chunk = wv * 4 + i;
      int r = chunk * 8 + (ln >> 3);
      const unsigned short* srcA =
          emb_bf + (size_t)xrow[i] * 512 + k0 + (((ln & 7) ^ (r & 7)) << 3);
      gload_lds16(srcA, &A_lds[buf][chunk * 512]);
      const unsigned short* srcB =
          W_sw + (size_t)(ntile * 128 + r) * 512 + k0 + ((ln & 7) << 3);
      gload_lds16(srcB, &B_lds[buf][chunk * 512]);
    }
  };

  f32x4 acc[4][4];
#pragma unroll
  for (int i = 0; i < 4; ++i)
#pragma unroll
    for (int j = 0; j < 4; ++j) acc[i][j] = (f32x4)0.0f;

  int wm = wv >> 1, wn = wv & 1;
  stage(0, 0);
#pragma unroll 1
  for (int kb = 0; kb < 8; ++kb) {
    __syncthreads();
    if (kb < 7) stage((kb + 1) & 1, kb + 1);
    int buf = kb & 1;
#pragma unroll
    for (int ks = 0; ks < 2; ++ks) {
      bf16x8 a[4], b[4];
#pragma unroll
      for (int f = 0; f < 4; ++f) {
        int r = wm * 64 + f * 16 + (ln & 15);
        int sa = ((ks * 4 + (ln >> 4)) ^ (r & 7)) & 7;
        a[f] = *(const bf16x8*)&A_lds[buf][r * 64 + sa * 8];
        int n = wn * 64 + f * 16 + (ln & 15);
        int sb = ((ks * 4 + (ln >> 4)) ^ (n & 7)) & 7;
        b[f] = *(const bf16x8*)&B_lds[buf][n * 64 + sb * 8];
      }
#pragma unroll
      for (int i = 0; i < 4; ++i)
#pragma unroll
        for (int j = 0; j < 4; ++j)
          acc[i][j] = __builtin_amdgcn_mfma_f32_16x16x32_bf16(a[i], b[j], acc[i][j], 0, 0, 0);
    }
  }
#pragma unroll
  for (int fm = 0; fm < 4; ++fm) {
#pragma unroll
    for (int fn = 0; fn < 4; ++fn) {
      int n = ntile * 128 + wn * 64 + fn * 16 + (ln & 15);
      float bn = bias[n];
      int m0 = mtile * 128 + wm * 64 + fm * 16 + ((ln >> 4) << 2);
#pragma unroll
      for (int i = 0; i < 4; ++i) {
        pre[(size_t)(m0 + i) * 4096 + n] = f2bf(acc[fm][fn][i] + bn);
      }
    }
  }
}

// ---------------- flag init ----------------
__global__ void init_flags(unsigned int* f) {
  __hip_atomic_store(&f[threadIdx.x], 0u, __ATOMIC_RELAXED, __HIP_MEMORY_SCOPE_AGENT);
}

// ---------------- persistent LSTM recurrence ----------------
// grid 256 = 4 batch-groups (32 rows) x 64 j-slices (16 hidden cols); 512 thr = 8 waves.
// PROVEN round-4 protocol (flags + explicit vmcnt(0) release drain + SYNC2; dedicated
// hbc/flags regions; agent-scope h stores/loads) with two deltas:
//  (1) fine-grained consume: wave wv polls only its 8 producers (js in [8wv,8wv+8)),
//      with an explicit compiler memory barrier after poll-exit so the relaxed-atomic
//      h loads can NEVER be compiler-reordered above the spin loop (suspected round-3
//      bug). Overwrite-safety: flag t+1 is published after SYNC2(t); reaching the h
//      store of step t+1 requires SYNC1(t+1), which joins all 8 waves whose polls
//      jointly saw ALL 64 flags >= t+1, i.e. every WG consumed h_{t-1}. Sound.
//  (2) pre prefetch moved AFTER the flag publish -> the release drain waits only on
//      the h/out stores; prefetch latency hides under the poll phase.
__global__ __launch_bounds__(512, 2) void lstm_kernel(
    const unsigned short* __restrict__ pre, const unsigned short* __restrict__ U_t,
    unsigned short* __restrict__ hbc, float* __restrict__ out, unsigned int* flags) {
  __shared__ float zbuf[8][32][68];  // [wave slice][row][z-col], padded
  int bid = blockIdx.x;
  int bg = bid >> 6, js = bid & 63;
  int tid = threadIdx.x, wv = tid >> 6, ln = tid & 63;

  // resident B fragments: ub[gate][kk]; col = gate*1024 + js*16 + (ln&15)
  bf16x8 ub[4][4];
#pragma unroll
  for (int f = 0; f < 4; ++f) {
    int col = f * 1024 + js * 16 + (ln & 15);
#pragma unroll
    for (int kk = 0; kk < 4; ++kk) {
      int k = wv * 128 + kk * 32 + ((ln >> 4) << 3);
      ub[f][kk] = *(const bf16x8*)&U_t[(size_t)col * 1024 + k];
    }
  }

  // gate-phase ownership: 512 threads = 32 rows x 16 j
  int row = tid >> 4, j = tid & 15;
  int b = bg * 32 + row;
  int hcol = js * 16 + j;
  float c_state = 0.0f;
  size_t preb = ((size_t)b * 256) * 4096 + (size_t)(js * 16 + j);
  size_t outb = ((size_t)b * 256) * 1024 + (size_t)hcol;
  int arow0 = bg * 32 + (ln & 15);
  int arow1 = arow0 + 16;
  const unsigned int* flp = flags + bg * 64 + (wv << 3) + (ln & 7);  // my 8 producers
  unsigned int* myflag = flags + bg * 64 + js;

  // prefetch pre[t=0]
  float z0n, z1n, z2n, z3n;
  {
    const unsigned short* pp = pre + preb;
    z0n = bf2f(pp[0]); z1n = bf2f(pp[1024]); z2n = bf2f(pp[2048]); z3n = bf2f(pp[3072]);
  }

#pragma unroll 1
  for (int t = 0; t < 256; ++t) {
    int p = t & 1;
    if (t > 0) {
      // per-wave: wait only for this wave's 8 producer WGs to publish h_{t-1}
      int guard = 0;
      while (!__all((int)(__hip_atomic_load(flp, __ATOMIC_RELAXED,
                                            __HIP_MEMORY_SCOPE_AGENT) >= (unsigned)t))) {
        if (++guard > 4000000) break;  // watchdog: fail fast+visibly, never hang
        __builtin_amdgcn_s_sleep(1);
      }
      // compiler memory barrier: h loads below must NOT be hoisted above the poll
      asm volatile("" ::: "memory");
      const unsigned short* hprev = hbc + (size_t)(p ^ 1) * 131072;
      f32x4 acc[2][4];
#pragma unroll
      for (int m = 0; m < 2; ++m)
#pragma unroll
        for (int f = 0; f < 4; ++f) acc[m][f] = (f32x4)0.0f;
#pragma unroll
      for (int kk = 0; kk < 4; ++kk) {
        int k = wv * 128 + kk * 32 + ((ln >> 4) << 3);
        bf16x8 a0 = loadh16(&hprev[(size_t)arow0 * 1024 + k]);
        bf16x8 a1 = loadh16(&hprev[(size_t)arow1 * 1024 + k]);
#pragma unroll
        for (int f = 0; f < 4; ++f) {
          acc[0][f] = __builtin_amdgcn_mfma_f32_16x16x32_bf16(a0, ub[f][kk], acc[0][f], 0, 0, 0);
          acc[1][f] = __builtin_amdgcn_mfma_f32_16x16x32_bf16(a1, ub[f][kk], acc[1][f], 0, 0, 0);
        }
      }
      // private-slice zbuf writes (2-way bank alias max)
#pragma unroll
      for (int m = 0; m < 2; ++m)
#pragma unroll
        for (int f = 0; f < 4; ++f)
#pragma unroll
          for (int i = 0; i < 4; ++i)
            zbuf[wv][m * 16 + ((ln >> 4) << 2) + i][f * 16 + (ln & 15)] = acc[m][f][i];
      __syncthreads();  // SYNC1: all z slices visible; joins all waves' polls
    }
    // gates (Keras order i,f,c,o) from prefetched pre values
    float z0 = z0n, z1 = z1n, z2 = z2n, z3 = z3n;
    if (t > 0) {
      float s0 = 0.f, s1 = 0.f, s2 = 0.f, s3 = 0.f;
#pragma unroll
      for (int s = 0; s < 8; ++s) {
        s0 += zbuf[s][row][j];
        s1 += zbuf[s][row][16 + j];
        s2 += zbuf[s][row][32 + j];
        s3 += zbuf[s][row][48 + j];
      }
      z0 += s0; z1 += s1; z2 += s2; z3 += s3;
    }
    float ig = sigm(z0), fg = sigm(z1), gg = tanh_f(z2), og = sigm(z3);
    c_state = fg * c_state + ig * gg;
    float h = og * tanh_f(c_state);
    // device-coherent h publish (write-through to the coherence point)
    __hip_atomic_store(&hbc[(size_t)p * 131072 + (size_t)b * 1024 + hcol], f2bf(h),
                       __ATOMIC_RELAXED, __HIP_MEMORY_SCOPE_AGENT);
    if (t == 255) {
      out[outb + (size_t)t * 1024] = h;
      out[33554432 + (size_t)b * 1024 + hcol] = h;
      out[33554432 + 131072 + (size_t)b * 1024 + hcol] = c_state;
    } else {
      // EXPLICIT release drain: every wave waits for its own h-store to reach the
      // coherence point BEFORE the barrier; the flag store after the barrier is then
      // ordered after ALL waves' h-stores. Also orders zbuf reads(t) vs writes(t+1).
      asm volatile("s_waitcnt vmcnt(0)" ::: "memory");
      __syncthreads();  // SYNC2
      if (tid == 0)
        __hip_atomic_store(myflag, (unsigned)(t + 1), __ATOMIC_RELAXED,
                           __HIP_MEMORY_SCOPE_AGENT);
      // bulk out store + next-step prefetch AFTER the publish: off the release path,
      // latency hides under the next poll phase.
      out[outb + (size_t)t * 1024] = h;
      const unsigned short* pp = pre + preb + (size_t)(t + 1) * 4096;
      z0n = bf2f(pp[0]); z1n = bf2f(pp[1024]); z2n = bf2f(pp[2048]); z3n = bf2f(pp[3072]);
    }
  }
}

// ---------------- launcher ----------------
extern "C" void kernel_launch(void* const* d_in, const int* in_sizes, int n_in,
                              void* d_out, int out_size, void* d_ws, size_t ws_size,
                              hipStream_t stream) {
  const int*   x    = (const int*)d_in[0];
  // d_in[1] = hidden (ignored by reference module)
  const float* emb  = (const float*)d_in[2];
  const float* W    = (const float*)d_in[3];
  const float* U    = (const float*)d_in[4];
  const float* bias = (const float*)d_in[5];
  float* out = (float*)d_out;

  // workspace layout (bytes) -- identical to the proven round-4 layout
  const size_t OFS_PRE = 0;                     // 32768*4096*2 = 268435456
  const size_t OFS_EMB = 268435456;             // 32000*512*2  = 32768000
  const size_t OFS_WSW = 301203456;             // 4096*512*2   = 4194304
  const size_t OFS_UT  = 305397760;             // 4096*1024*2  = 8388608
  const size_t OFS_HBC = 313786368;             // 2*128*1024*2 = 524288
  const size_t OFS_FLG = 314310656;             // 256 * 4B     = 1024
  const size_t WS_NEED = 314311680;
  if (ws_size < WS_NEED) return;  // insufficient scratch -> fail validation visibly

  char* ws = (char*)d_ws;
  unsigned short* pre_p = (unsigned short*)(ws + OFS_PRE);
  unsigned short* emb_p = (unsigned short*)(ws + OFS_EMB);
  unsigned short* wsw_p = (unsigned short*)(ws + OFS_WSW);
  unsigned short* ut_p  = (unsigned short*)(ws + OFS_UT);
  unsigned short* hbc_p = (unsigned short*)(ws + OFS_HBC);
  unsigned int*   flg_p = (unsigned int*)(ws + OFS_FLG);

  cvt_bf16_vec<<<2048, 256, 0, stream>>>((const float4*)emb, (ushort4*)emb_p, 4096000);
  transpose_cvt<1><<<dim3(8, 64), 256, 0, stream>>>(W, wsw_p, 512, 4096);
  transpose_cvt<0><<<dim3(16, 64), 256, 0, stream>>>(U, ut_p, 1024, 4096);
  init_flags<<<1, 256, 0, stream>>>(flg_p);
  pregemm<<<8192, 256, 0, stream>>>(emb_p, x, wsw_p, bias, pre_p);

  const unsigned short* pre_c = pre_p;
  const unsigned short* ut_c  = ut_p;
  unsigned short* hbc_v = hbc_p;
  float* out_v = out;
  unsigned int* flg_v = flg_p;
  void* args[] = {(void*)&pre_c, (void*)&ut_c, (void*)&hbc_v, (void*)&out_v, (void*)&flg_v};
  hipLaunchCooperativeKernel((const void*)lstm_kernel, dim3(256), dim3(512), args, 0, stream);
}